// Round 16
// baseline (94.333 us; speedup 1.0000x reference)
//
#include <hip/hip_runtime.h>

#define Dq    256
#define ATTR  400
#define HW    3136
#define NB    32
#define P     224           // px per block
#define NTX   14            // tiles per batch row (14*224 = 3136)
#define SLABB 28672         // 32ch * 224px * 4B slab bytes

typedef __attribute__((ext_vector_type(8))) short bf16x8;
typedef __attribute__((ext_vector_type(4))) float f32x4;

__device__ __forceinline__ unsigned short f2bf(float f) {
  unsigned int x = __float_as_uint(f);
  return (unsigned short)((x + 0x7FFFu + ((x >> 16) & 1u)) >> 16);
}

__device__ __forceinline__ void g2lds16(const float* g, float* l) {
  __builtin_amdgcn_global_load_lds(
      (const __attribute__((address_space(1))) unsigned int*)g,
      (__attribute__((address_space(3))) unsigned int*)l,
      16, 0, 0);
}

// ---------------- Kernel A: per-batch count-sketch vector sk1[b][256] ----------------
__global__ __launch_bounds__(256) void k_sk1(
    const float* __restrict__ oh, const float* __restrict__ W_emb,
    const float* __restrict__ b_emb, const float* __restrict__ conv_w,
    const float* __restrict__ conv_b, const int* __restrict__ h1,
    const float* __restrict__ s1, float* __restrict__ sk1_out) {
  __shared__ float ohs[ATTR];
  __shared__ float ts[Dq];
  __shared__ float sk[Dq];
  const int b = blockIdx.x, tid = threadIdx.x;
  for (int j = tid; j < ATTR; j += 256) ohs[j] = oh[b * ATTR + j];
  sk[tid] = 0.f;
  __syncthreads();
  float acc = b_emb[tid];
  const float* wr = W_emb + tid * ATTR;
  for (int j = 0; j < ATTR; ++j) acc = fmaf(ohs[j], wr[j], acc);
  ts[tid] = acc;
  __syncthreads();
  float a = conv_b[tid];
  const float* cr = conv_w + tid * Dq;
  for (int k = 0; k < Dq; ++k) a = fmaf(ts[k], cr[k], a);
  atomicAdd(&sk[h1[tid]], a * s1[tid]);
  __syncthreads();
  sk1_out[b * Dq + tid] = sk[tid];
}

// ---------------- Kernel B: circular conv + scatter into MFMA A-fragment layout ----------------
// A[m=o][k=c] = G[b][c][o] = s2[c] * T[o,h2[c]]:
//   frag = (o>>4)*8 + (c>>5), lane = (o&15) | (((c>>3)&3)<<4), j = c&7.
__global__ __launch_bounds__(256) void k_G(
    const float* __restrict__ sk1, const float* __restrict__ conv1_w,
    const int* __restrict__ h2, const float* __restrict__ s2,
    unsigned short* __restrict__ Abuf) {
  __shared__ float sks[Dq];
  __shared__ float w1[Dq];
  __shared__ float Tl[Dq];
  const int b = blockIdx.x >> 5, o = blockIdx.x & 31, c = threadIdx.x;
  sks[c] = sk1[b * Dq + c];
  w1[c]  = conv1_w[o * Dq + c];
  __syncthreads();
  float t = 0.f;
  for (int d = 0; d < Dq; ++d) t = fmaf(w1[d], sks[(d - c) & 255], t);
  Tl[c] = t;
  __syncthreads();
  const float g = s2[c] * Tl[h2[c]];
  const int frag = (o >> 4) * 8 + (c >> 5);
  const int lane = (o & 15) | (((c >> 3) & 3) << 4);
  Abuf[(((size_t)b * 16 + frag) * 64 + lane) * 8 + (c & 7)] = f2bf(g);
}

// ---------------- Kernel BIG: K-slab GEMM gate + in-block stream multiply ----------------
// Block = 256 thr (4 waves), px window = 224 (runs of 896B). Gate streams 8
// channel-slabs of 32 through double-buffered LDS (2x28KB) via global_load_lds
// with counted vmcnt(7); A-fragments for all 8 slabs preloaded to VGPRs so
// in-loop vmcnt counts ONLY stage DMA. Wave w owns px tiles {w, w+4, w+8,
// w+12<14}. Pass 2: pure register stream (load f32x4, mul by s, store) over
// the same window - dense sequential sweeps, L3-hot reads.
__global__ __launch_bounds__(256) void k_big(
    const float* __restrict__ ent,            // [B,256,HW]
    const unsigned short* __restrict__ Abuf,  // [B,16,64,8]
    const float* __restrict__ c1b, const float* __restrict__ c2w,
    const float* __restrict__ c2b,
    float* __restrict__ out)                  // map [B,HW] then feat [B,256,HW]
{
  __shared__ float buf[2][SLABB / 4];         // 2 x 28 KB, slab layout [32ch][224px]
  __shared__ float s_lds[P];
  const int t = threadIdx.x;
  const int w = t >> 6, l = t & 63;
  const int n = l & 15, kg = l >> 4;
  const int b = blockIdx.x / NTX, tix = blockIdx.x % NTX;
  const int px_base = tix * P;

  const float* eb = ent + (size_t)b * Dq * HW + px_base;

  // ---- preload all 16 A-fragments (2 otiles x 8 slabs), 16B/lane, L2-hot ----
  const unsigned short* Ab = Abuf + ((size_t)b * 16 * 64 + l) * 8;
  bf16x8 A0[8], A1[8];
#pragma unroll
  for (int k = 0; k < 8; ++k) {
    A0[k] = *reinterpret_cast<const bf16x8*>(Ab + (size_t)(0 * 8 + k) * 64 * 8);
    A1[k] = *reinterpret_cast<const bf16x8*>(Ab + (size_t)(1 * 8 + k) * 64 * 8);
  }

  const float4 b1a = reinterpret_cast<const float4*>(c1b)[kg];
  const float4 b1b = reinterpret_cast<const float4*>(c1b)[kg + 4];
  const float4 w2a = reinterpret_cast<const float4*>(c2w)[kg];
  const float4 w2b = reinterpret_cast<const float4*>(c2w)[kg + 4];
  const float c2b0 = c2b[0];

  // stage slab `sl` into buf[bs]: 7 instrs/wave, dest linear, src per-lane
#define STAGE(sl, bs)                                                          \
  {                                                                            \
    const float* sb = eb + (size_t)(sl) * 32 * HW;                             \
    _Pragma("unroll")                                                          \
    for (int i = 0; i < 7; ++i) {                                              \
      const int dbase = i * 4096 + w * 1024;                                   \
      const int dl = dbase + l * 16;                                           \
      const int cc = dl / 896;                                                 \
      const int off = dl - cc * 896;                                           \
      g2lds16(sb + (size_t)cc * HW + (off >> 2), &buf[bs][dbase >> 2]);        \
    }                                                                          \
  }

  f32x4 acc[4][2];
#pragma unroll
  for (int ii = 0; ii < 4; ++ii) { acc[ii][0] = f32x4{0,0,0,0}; acc[ii][1] = f32x4{0,0,0,0}; }

  STAGE(0, 0);
  int cur = 0;
#pragma unroll
  for (int k = 0; k < 8; ++k) {
    if (k < 7) {
      STAGE(k + 1, cur ^ 1);
      asm volatile("s_waitcnt vmcnt(7)" ::: "memory");
    } else {
      asm volatile("s_waitcnt vmcnt(0)" ::: "memory");
    }
    __builtin_amdgcn_sched_barrier(0);
    __builtin_amdgcn_s_barrier();      // slab k fully landed (all waves waited)

    const float* tb = &buf[cur][0];
#pragma unroll
    for (int ii = 0; ii < 4; ++ii) {
      const int ti = w + 4 * ii;
      if (ti < NTX) {
        bf16x8 bv;
#pragma unroll
        for (int j = 0; j < 8; ++j) {
          const float fv = tb[(kg * 8 + j) * P + ti * 16 + n];
          bv[j] = (short)f2bf(fmaxf(fv, 0.f));
        }
        acc[ii][0] = __builtin_amdgcn_mfma_f32_16x16x32_bf16(A0[k], bv, acc[ii][0], 0, 0, 0);
        acc[ii][1] = __builtin_amdgcn_mfma_f32_16x16x32_bf16(A1[k], bv, acc[ii][1], 0, 0, 0);
      }
    }
    __builtin_amdgcn_s_barrier();      // all waves done reading buf[cur]
    cur ^= 1;
  }

  // ---- epilogue: per px-tile gate reduce + sigmoid -> map + s_lds ----
#pragma unroll
  for (int ii = 0; ii < 4; ++ii) {
    const int ti = w + 4 * ii;
    if (ti < NTX) {
      float z = 0.f;
      z = fmaf(w2a.x, fmaxf(acc[ii][0][0] + b1a.x, 0.f), z);
      z = fmaf(w2a.y, fmaxf(acc[ii][0][1] + b1a.y, 0.f), z);
      z = fmaf(w2a.z, fmaxf(acc[ii][0][2] + b1a.z, 0.f), z);
      z = fmaf(w2a.w, fmaxf(acc[ii][0][3] + b1a.w, 0.f), z);
      z = fmaf(w2b.x, fmaxf(acc[ii][1][0] + b1b.x, 0.f), z);
      z = fmaf(w2b.y, fmaxf(acc[ii][1][1] + b1b.y, 0.f), z);
      z = fmaf(w2b.z, fmaxf(acc[ii][1][2] + b1b.z, 0.f), z);
      z = fmaf(w2b.w, fmaxf(acc[ii][1][3] + b1b.w, 0.f), z);
      z += __shfl_xor(z, 16);
      z += __shfl_xor(z, 32);
      const float s = 1.f / (1.f + __expf(-(z + c2b0)));
      if (kg == 0) {
        out[(size_t)b * HW + px_base + ti * 16 + n] = s;
        s_lds[ti * 16 + n] = s;
      }
    }
  }
  __syncthreads();

  // ---- pass 2: dense stream multiply over [256 ch][224 px] window ----
  const f32x4* eb4 = reinterpret_cast<const f32x4*>(eb);
  f32x4* fb4 = reinterpret_cast<f32x4*>(out + (size_t)NB * HW + (size_t)b * Dq * HW + px_base);
  const f32x4* sl4 = reinterpret_cast<const f32x4*>(s_lds);
#pragma unroll 4
  for (int k2 = 0; k2 < 56; ++k2) {
    const int u = k2 * 256 + t;          // 0..14335 over (c,q)
    const int c = u / 56;
    const int q = u - c * 56;
    f32x4 e = eb4[c * 784 + q];          // 784 = HW/4
    f32x4 r = e * sl4[q];
    fb4[c * 784 + q] = r;
  }
}

extern "C" void kernel_launch(void* const* d_in, const int* in_sizes, int n_in,
                              void* d_out, int out_size, void* d_ws, size_t ws_size,
                              hipStream_t stream) {
  const float* ent    = (const float*)d_in[0];
  const float* oh     = (const float*)d_in[1];
  const float* W_emb  = (const float*)d_in[2];
  const float* b_emb  = (const float*)d_in[3];
  const float* conv_w = (const float*)d_in[4];
  const float* conv_b = (const float*)d_in[5];
  const float* c1w    = (const float*)d_in[6];
  const float* c1b    = (const float*)d_in[7];
  const float* c2w    = (const float*)d_in[8];
  const float* c2b    = (const float*)d_in[9];
  const int*   h1     = (const int*)d_in[10];
  const int*   h2     = (const int*)d_in[11];
  const float* s1     = (const float*)d_in[12];
  const float* s2     = (const float*)d_in[13];

  float* ws  = (float*)d_ws;
  float* sk1 = ws;                                        // 32*256 f32
  unsigned short* Abuf = (unsigned short*)(ws + NB * Dq); // 32*16*64*8 bf16

  hipLaunchKernelGGL(k_sk1, dim3(NB), dim3(256), 0, stream,
                     oh, W_emb, b_emb, conv_w, conv_b, h1, s1, sk1);
  hipLaunchKernelGGL(k_G, dim3(NB * 32), dim3(256), 0, stream,
                     sk1, c1w, h2, s2, Abuf);
  hipLaunchKernelGGL(k_big, dim3(NB * NTX), dim3(256), 0, stream,
                     ent, Abuf, c1b, c2w, c2b, (float*)d_out);
}

// Round 17
// 87.432 us; speedup vs baseline: 1.0789x; 1.0789x over previous
//
#include <hip/hip_runtime.h>

#define Dq    256
#define ATTR  400
#define HW    3136
#define NB    32
#define PXT   64      // pixel tile per k_map block
#define NTILE 49      // HW/PXT

typedef __attribute__((ext_vector_type(8))) short bf16x8;
typedef __attribute__((ext_vector_type(4))) float f32x4;

__device__ __forceinline__ unsigned short f2bf(float f) {
  unsigned int x = __float_as_uint(f);
  return (unsigned short)((x + 0x7FFFu + ((x >> 16) & 1u)) >> 16);
}

__device__ __forceinline__ void g2lds16(const float* g, float* l) {
  __builtin_amdgcn_global_load_lds(
      (const __attribute__((address_space(1))) unsigned int*)g,
      (__attribute__((address_space(3))) unsigned int*)l,
      16, 0, 0);
}

// ---------------- Kernel A: per-batch count-sketch vector sk1[b][256] ----------------
__global__ __launch_bounds__(256) void k_sk1(
    const float* __restrict__ oh, const float* __restrict__ W_emb,
    const float* __restrict__ b_emb, const float* __restrict__ conv_w,
    const float* __restrict__ conv_b, const int* __restrict__ h1,
    const float* __restrict__ s1, float* __restrict__ sk1_out) {
  __shared__ float ohs[ATTR];
  __shared__ float ts[Dq];
  __shared__ float sk[Dq];
  const int b = blockIdx.x, tid = threadIdx.x;
  for (int j = tid; j < ATTR; j += 256) ohs[j] = oh[b * ATTR + j];
  sk[tid] = 0.f;
  __syncthreads();
  float acc = b_emb[tid];
  const float* wr = W_emb + tid * ATTR;
  for (int j = 0; j < ATTR; ++j) acc = fmaf(ohs[j], wr[j], acc);
  ts[tid] = acc;
  __syncthreads();
  float a = conv_b[tid];
  const float* cr = conv_w + tid * Dq;
  for (int k = 0; k < Dq; ++k) a = fmaf(ts[k], cr[k], a);
  atomicAdd(&sk[h1[tid]], a * s1[tid]);
  __syncthreads();
  sk1_out[b * Dq + tid] = sk[tid];
}

// ---------------- Kernel B: circular conv + scatter into MFMA A-fragment layout ----------------
// A[m=o][k=c] = G[b][c][o] = s2[c] * T[o,h2[c]]:
//   frag = (o>>4)*8 + (c>>5), lane = (o&15) | (((c>>3)&3)<<4), j = c&7.
__global__ __launch_bounds__(256) void k_G(
    const float* __restrict__ sk1, const float* __restrict__ conv1_w,
    const int* __restrict__ h2, const float* __restrict__ s2,
    unsigned short* __restrict__ Abuf) {
  __shared__ float sks[Dq];
  __shared__ float w1[Dq];
  __shared__ float Tl[Dq];
  const int b = blockIdx.x >> 5, o = blockIdx.x & 31, c = threadIdx.x;
  sks[c] = sk1[b * Dq + c];
  w1[c]  = conv1_w[o * Dq + c];
  __syncthreads();
  float t = 0.f;
  for (int d = 0; d < Dq; ++d) t = fmaf(w1[d], sks[(d - c) & 255], t);
  Tl[c] = t;
  __syncthreads();
  const float g = s2[c] * Tl[h2[c]];
  const int frag = (o >> 4) * 8 + (c >> 5);
  const int lane = (o & 15) | (((c >> 3) & 3) << 4);
  Abuf[(((size_t)b * 16 + frag) * 64 + lane) * 8 + (c & 7)] = f2bf(g);
}

// ---------------- Kernel MAP: global_load_lds stage -> MFMA gate -> map only ----------------
// Round-14 structure WITHOUT the feature-store phase. Block = 256 thr, tile
// [256 ch][64 px] f32 linear in LDS (64 KB, 2 blocks/CU). Writes only the
// 4-byte/px attr_map.
__global__ __launch_bounds__(256) void k_map(
    const float* __restrict__ ent,            // [B,256,HW]
    const unsigned short* __restrict__ Abuf,  // [B,16,64,8]
    const float* __restrict__ c1b, const float* __restrict__ c2w,
    const float* __restrict__ c2b,
    float* __restrict__ out)                  // map [B,HW] at offset 0
{
  __shared__ float tile[Dq * PXT];            // 64 KB linear [c][64]
  const int b = blockIdx.y;
  const int px_base = blockIdx.x * PXT;
  const int t = threadIdx.x;
  const int w = t >> 6, l = t & 63;

  const float* eb = ent + (size_t)b * Dq * HW + px_base;

  // stage: wave w covers channels [w*64,(w+1)*64), 16 async 1KB copies
#pragma unroll
  for (int i = 0; i < 16; ++i) {
    const int cb = w * 64 + i * 4;
    g2lds16(eb + (size_t)(cb + (l >> 4)) * HW + 4 * (l & 15), &tile[cb * PXT]);
  }
  asm volatile("s_waitcnt vmcnt(0)");
  __syncthreads();

  // gate: wave w owns px subtile [w*16,(w+1)*16)
  const int n = l & 15, kg = l >> 4;
  const unsigned short* Ab = Abuf + ((size_t)b * 16 * 64 + l) * 8;

  f32x4 acc0 = {0.f, 0.f, 0.f, 0.f}, acc1 = {0.f, 0.f, 0.f, 0.f};
#pragma unroll
  for (int ks = 0; ks < 8; ++ks) {
    bf16x8 bv;
#pragma unroll
    for (int j = 0; j < 8; ++j) {
      const float fv = tile[(ks * 32 + kg * 8 + j) * PXT + w * 16 + n];
      bv[j] = (short)f2bf(fmaxf(fv, 0.f));
    }
    bf16x8 a0 = *reinterpret_cast<const bf16x8*>(Ab + (size_t)(0 * 8 + ks) * 64 * 8);
    bf16x8 a1 = *reinterpret_cast<const bf16x8*>(Ab + (size_t)(1 * 8 + ks) * 64 * 8);
    acc0 = __builtin_amdgcn_mfma_f32_16x16x32_bf16(a0, bv, acc0, 0, 0, 0);
    acc1 = __builtin_amdgcn_mfma_f32_16x16x32_bf16(a1, bv, acc1, 0, 0, 0);
  }

  const float4 b1a = reinterpret_cast<const float4*>(c1b)[kg];
  const float4 b1b = reinterpret_cast<const float4*>(c1b)[kg + 4];
  const float4 w2a = reinterpret_cast<const float4*>(c2w)[kg];
  const float4 w2b = reinterpret_cast<const float4*>(c2w)[kg + 4];
  float z = 0.f;
  z = fmaf(w2a.x, fmaxf(acc0[0] + b1a.x, 0.f), z);
  z = fmaf(w2a.y, fmaxf(acc0[1] + b1a.y, 0.f), z);
  z = fmaf(w2a.z, fmaxf(acc0[2] + b1a.z, 0.f), z);
  z = fmaf(w2a.w, fmaxf(acc0[3] + b1a.w, 0.f), z);
  z = fmaf(w2b.x, fmaxf(acc1[0] + b1b.x, 0.f), z);
  z = fmaf(w2b.y, fmaxf(acc1[1] + b1b.y, 0.f), z);
  z = fmaf(w2b.z, fmaxf(acc1[2] + b1b.z, 0.f), z);
  z = fmaf(w2b.w, fmaxf(acc1[3] + b1b.w, 0.f), z);
  z += __shfl_xor(z, 16);
  z += __shfl_xor(z, 32);
  const float s = 1.f / (1.f + __expf(-(z + c2b[0])));
  if (l < 16) out[(size_t)b * HW + px_base + w * 16 + l] = s;
}

// ---------------- Kernel MUL: perfectly linear feature stream ----------------
// feature and entity share the [B,256,HW] flat layout: feat4[f] = e4[f] *
// s4[b*784 + q], f in f32x4 units. 1792 blocks x 256 thr x 14 f32x4; each
// block owns a CONTIGUOUS 56 KB output chunk, consecutive threads ->
// consecutive 16B. Entity read is L3-hot (just streamed by k_map);
// nontemporal full-line writes go straight to HBM without evicting it.
__global__ __launch_bounds__(256) void k_mul(
    const float* __restrict__ ent, float* __restrict__ out) {
  const f32x4* e4 = reinterpret_cast<const f32x4*>(ent);
  const f32x4* m4 = reinterpret_cast<const f32x4*>(out);          // map region
  f32x4* f4 = reinterpret_cast<f32x4*>(out + (size_t)NB * HW);
  const int base = blockIdx.x * 3584 + threadIdx.x;
#pragma unroll
  for (int i = 0; i < 14; ++i) {
    const int f = base + i * 256;            // f32x4 flat index, < 6,422,528
    const int r = f / 784;                   // channel-row (b*256 + c)
    const int q = f - r * 784;               // f32x4 index within row
    const int b = r >> 8;
    f32x4 v = e4[f] * m4[b * 784 + q];
    __builtin_nontemporal_store(v, &f4[f]);
  }
}

extern "C" void kernel_launch(void* const* d_in, const int* in_sizes, int n_in,
                              void* d_out, int out_size, void* d_ws, size_t ws_size,
                              hipStream_t stream) {
  const float* ent    = (const float*)d_in[0];
  const float* oh     = (const float*)d_in[1];
  const float* W_emb  = (const float*)d_in[2];
  const float* b_emb  = (const float*)d_in[3];
  const float* conv_w = (const float*)d_in[4];
  const float* conv_b = (const float*)d_in[5];
  const float* c1w    = (const float*)d_in[6];
  const float* c1b    = (const float*)d_in[7];
  const float* c2w    = (const float*)d_in[8];
  const float* c2b    = (const float*)d_in[9];
  const int*   h1     = (const int*)d_in[10];
  const int*   h2     = (const int*)d_in[11];
  const float* s1     = (const float*)d_in[12];
  const float* s2     = (const float*)d_in[13];

  float* ws  = (float*)d_ws;
  float* sk1 = ws;                                        // 32*256 f32
  unsigned short* Abuf = (unsigned short*)(ws + NB * Dq); // 32*16*64*8 bf16

  hipLaunchKernelGGL(k_sk1, dim3(NB), dim3(256), 0, stream,
                     oh, W_emb, b_emb, conv_w, conv_b, h1, s1, sk1);
  hipLaunchKernelGGL(k_G, dim3(NB * 32), dim3(256), 0, stream,
                     sk1, c1w, h2, s2, Abuf);
  hipLaunchKernelGGL(k_map, dim3(NTILE, NB), dim3(256), 0, stream,
                     ent, Abuf, c1b, c2w, c2b, (float*)d_out);
  hipLaunchKernelGGL(k_mul, dim3(1792), dim3(256), 0, stream,
                     ent, (float*)d_out);
}